// Round 11
// baseline (195.875 us; speedup 1.0000x reference)
//
#include <hip/hip_runtime.h>

// SSD target assignment for MI355X.
// B=64, N=64 objects, A=24564 anchors. Outputs f32: classes|locations|masks.
//
// 3 kernels:
//   k_init  : zero per-object argmax keys (u64[BN])
//   k_iou   : the single B*N*A IoU pass. Per-anchor row argmax -> pbest[B*A];
//             per-object column argmax via DPP wave reduction + u64 atomicMax.
//   k_final : div-free force-match + threshold + encode + store.
//
// ws: keys u64[BN] | pbest u64[BA]  (~12.6 MB; harness ws is larger - verified r10)

#define NOBJ 64
#define VEC 4
#define FSENT 64

// DPP lane-shift helper (bound_ctrl=1 -> out-of-range lanes read 0).
#define DPP0(x, ctrl) __builtin_amdgcn_update_dpp(0, (x), (ctrl), 0xF, 0xF, true)

// Inclusive wave-64 max; full-wave max lands in lane 63. Valid for x >= 0
// (DPP fill value 0 is neutral). row_shr:1/2/4/8 then row_bcast:15/31.
__device__ __forceinline__ float wave_max_f(float x) {
    x = fmaxf(x, __int_as_float(DPP0(__float_as_int(x), 0x111)));
    x = fmaxf(x, __int_as_float(DPP0(__float_as_int(x), 0x112)));
    x = fmaxf(x, __int_as_float(DPP0(__float_as_int(x), 0x114)));
    x = fmaxf(x, __int_as_float(DPP0(__float_as_int(x), 0x118)));
    x = fmaxf(x, __int_as_float(DPP0(__float_as_int(x), 0x142)));
    x = fmaxf(x, __int_as_float(DPP0(__float_as_int(x), 0x143)));
    return x;
}
__device__ __forceinline__ unsigned wave_max_u(unsigned x) {
    x = max(x, (unsigned)DPP0((int)x, 0x111));
    x = max(x, (unsigned)DPP0((int)x, 0x112));
    x = max(x, (unsigned)DPP0((int)x, 0x114));
    x = max(x, (unsigned)DPP0((int)x, 0x118));
    x = max(x, (unsigned)DPP0((int)x, 0x142));
    x = max(x, (unsigned)DPP0((int)x, 0x143));
    return x;
}

__global__ void k_init(unsigned long long* __restrict__ keys, int BN) {
    int i = blockIdx.x * blockDim.x + threadIdx.x;
    if (i < BN) keys[i] = 0ull;
}

// grid = (ceil(A/1024), B), block 256 = 4 waves; each wave owns 256 anchors (VEC=4/lane).
__global__ __launch_bounds__(256) void k_iou(
    const float4* __restrict__ gt_boxes,      // [B,N] corner boxes
    const float4* __restrict__ center_anchor, // [A] cx,cy,w,h
    unsigned long long* __restrict__ keys,    // [B,N] col-argmax keys (iou<<32|~aidx)
    unsigned long long* __restrict__ pbest,   // [B,A] row best (iou<<32|n)
    int A, int N)
{
#pragma clang fp contract(off)
    const int b     = blockIdx.y;
    const int wv    = threadIdx.x >> 6;
    const int lane  = threadIdx.x & 63;
    const int wbase = (blockIdx.x * 4 + wv) * (64 * VEC);
    const int bN    = b * N;

    // preload VEC anchors/lane; tail lanes clamp to A-1 (duplicate work is
    // value-identical -> benign for both argmaxes and the pbest store).
    float ax0[VEC], ay0[VEC], ax1[VEC], ay1[VEC], aar[VEC];
    int   aidx[VEC];
#pragma unroll
    for (int v = 0; v < VEC; ++v) {
        int a = wbase + v * 64 + lane;
        if (a >= A) a = A - 1;
        aidx[v] = a;
        float4 ca = center_anchor[a];
        float hw = ca.z * 0.5f, hh = ca.w * 0.5f;
        ax0[v] = ca.x - hw; ay0[v] = ca.y - hh;
        ax1[v] = ca.x + hw; ay1[v] = ca.y + hh;
        aar[v] = (ax1[v] - ax0[v]) * (ay1[v] - ay0[v]);   // ref: area from corners
    }
    float bv[VEC]; int bn[VEC];
#pragma unroll
    for (int v = 0; v < VEC; ++v) { bv[v] = -1.0f; bn[v] = 0; }

    for (int n = 0; n < NOBJ; ++n) {
        const float4 bx  = gt_boxes[bN + n];                 // wave-uniform
        const float  bar = (bx.z - bx.x) * (bx.w - bx.y);    // ref op-order
        float mv = -1.0f; int ma = 0;
#pragma unroll
        for (int v = 0; v < VEC; ++v) {
            float ltx = fmaxf(ax0[v], bx.x), lty = fmaxf(ay0[v], bx.y);
            float rbx = fminf(ax1[v], bx.z), rby = fminf(ay1[v], bx.w);
            float wx = fmaxf(rbx - ltx, 0.0f), wy = fmaxf(rby - lty, 0.0f);
            float inter = wx * wy;
            float iou = inter / ((aar[v] + bar) - inter);    // IEEE div, un-fused
            if (iou > bv[v]) { bv[v] = iou; bn[v] = n; }     // row first-max over n
            if (iou > mv)    { mv = iou;    ma = aidx[v]; }  // col first-max (asc v)
        }
        // column reduce across the wave: max value, then min anchor idx among ties
        float r = wave_max_f(mv);                            // iou >= 0 -> DPP-0 safe
        unsigned wmb = (unsigned)__builtin_amdgcn_readlane(__float_as_int(r), 63);
        float wmax = __uint_as_float(wmb);
        unsigned c = (mv == wmax) ? ~(unsigned)ma : 0u;      // ~idx: max == smallest idx
        c = wave_max_u(c);
        unsigned wc = (unsigned)__builtin_amdgcn_readlane((int)c, 63);
        if (lane == 0)
            atomicMax(&keys[bN + n], ((unsigned long long)wmb << 32) | wc);
    }
    const size_t base = (size_t)b * A;
#pragma unroll
    for (int v = 0; v < VEC; ++v) {
        pbest[base + aidx[v]] =
            ((unsigned long long)__float_as_uint(bv[v]) << 32) |
            (unsigned long long)(unsigned)bn[v];
    }
}

// grid = (ceil(A/256), B), block 256. No IoU divisions here.
__global__ __launch_bounds__(256) void k_final(
    const float4* __restrict__ gt_boxes,      // [B,N]
    const int*    __restrict__ gt_labels,     // [B,N]
    const float4* __restrict__ center_anchor, // [A]
    const unsigned long long* __restrict__ keys,  // [B,N]
    const unsigned long long* __restrict__ pbest, // [B,A]
    float* __restrict__ out, int A, int N, int BA)
{
#pragma clang fp contract(off)
    __shared__ float4 sbox[NOBJ];
    __shared__ int    slab[NOBJ];
    __shared__ int    sfo[NOBJ];   // forced anchor idx per object
    const int b = blockIdx.y, tid = threadIdx.x, bN = b * N;
    if (tid < NOBJ) {
        sbox[tid] = gt_boxes[bN + tid];
        slab[tid] = gt_labels[bN + tid];
        sfo[tid]  = (int)(~(unsigned)(keys[bN + tid] & 0xffffffffull));
    }
    __syncthreads();

    const int a = blockIdx.x * 256 + tid;
    if (a >= A) return;
    const size_t ia = (size_t)b * A + a;

    const unsigned long long pb = pbest[ia];
    const float bvv = __uint_as_float((unsigned)(pb >> 32));
    const int   bnn = (int)(pb & 0xffffffffull);

    // fid = smallest object index force-matched to this anchor (or FSENT)
    int fid = FSENT;
#pragma unroll
    for (int n = 0; n < NOBJ; ++n) {
        int cn = (sfo[n] == a) ? n : FSENT;
        fid = min(fid, cn);
    }

    bool pos; int best;
    if (fid != FSENT) {
        pos  = true;   // forced 1.0 in row
        best = (bvv == 1.0f && bnn < fid) ? bnn : fid;   // numpy first-max on modified row
    } else {
        pos  = (bvv >= 0.5f);
        best = bnn;
    }
    const int cls = pos ? (slab[best] + 1) : 0;

    const float4 ca = center_anchor[a];
    const float4 gb = sbox[best];
    const float gcx = (gb.x + gb.z) * 0.5f;
    const float gcy = (gb.y + gb.w) * 0.5f;
    const float gw  = gb.z - gb.x;
    const float gh  = gb.w - gb.y;
    const float l0 = (gcx - ca.x) / (ca.z / 10.0f);
    const float l1 = (gcy - ca.y) / (ca.w / 10.0f);
    const float l2 = __logf(gw / ca.z) * 5.0f;
    const float l3 = __logf(gh / ca.w) * 5.0f;

    const int idx = b * A + a;
    out[idx] = (float)cls;                                   // classes
    reinterpret_cast<float4*>(out + (size_t)BA)[idx] =
        make_float4(l0, l1, l2, l3);                         // locations
    out[(size_t)5 * BA + idx] = pos ? 1.0f : 0.0f;           // masks
}

extern "C" void kernel_launch(void* const* d_in, const int* in_sizes, int n_in,
                              void* d_out, int out_size, void* d_ws, size_t ws_size,
                              hipStream_t stream) {
    const float4* gt_boxes      = (const float4*)d_in[0];
    const int*    gt_labels     = (const int*)d_in[1];
    const float4* center_anchor = (const float4*)d_in[2];

    const int N  = NOBJ;
    const int BN = in_sizes[1];       // B*N
    const int B  = BN / N;
    const int A  = in_sizes[2] / 4;
    const int BA = B * A;
    float* out = (float*)d_out;

    char* w = (char*)d_ws;
    unsigned long long* keys  = (unsigned long long*)w;                 // 32 KB
    unsigned long long* pbest = (unsigned long long*)(w + (size_t)BN * 8);

    k_init<<<(BN + 255) / 256, 256, 0, stream>>>(keys, BN);

    const int APB = 4 * 64 * VEC;                 // 1024 anchors per block
    dim3 g1((A + APB - 1) / APB, B);              // (24, 64)
    k_iou<<<g1, 256, 0, stream>>>(gt_boxes, center_anchor, keys, pbest, A, N);

    dim3 g2((A + 255) / 256, B);                  // (96, 64)
    k_final<<<g2, 256, 0, stream>>>(gt_boxes, gt_labels, center_anchor,
                                    keys, pbest, out, A, N, BA);
}

// Round 15
// 194.737 us; speedup vs baseline: 1.0058x; 1.0058x over previous
//
#include <hip/hip_runtime.h>

// SSD target assignment for MI355X.
// B=64, N=64 objects, A=24564 anchors. Outputs f32: classes|locations|masks.
//
// 3 kernels (r11 structure; k_iou gets __launch_bounds__(256,4) so the
// allocator keeps the 4-anchor state in registers instead of rematerializing):
//   k_init  : zero per-object argmax keys (u64[BN])
//   k_iou   : single B*N*A IoU pass. Row argmax -> pbest[B*A]; col argmax via
//             DPP wave reduction + u64 atomicMax.
//   k_final : div-free force-match + threshold + encode + store.
// ws: keys u64[BN] | pbest u64[BA]

#define NOBJ 64
#define VEC 4
#define FSENT 64

#define DPP0(x, ctrl) __builtin_amdgcn_update_dpp(0, (x), (ctrl), 0xF, 0xF, true)

// Inclusive wave-64 max; result in lane 63. Valid for x >= 0 (DPP fill = 0).
__device__ __forceinline__ float wave_max_f(float x) {
    x = fmaxf(x, __int_as_float(DPP0(__float_as_int(x), 0x111)));
    x = fmaxf(x, __int_as_float(DPP0(__float_as_int(x), 0x112)));
    x = fmaxf(x, __int_as_float(DPP0(__float_as_int(x), 0x114)));
    x = fmaxf(x, __int_as_float(DPP0(__float_as_int(x), 0x118)));
    x = fmaxf(x, __int_as_float(DPP0(__float_as_int(x), 0x142)));
    x = fmaxf(x, __int_as_float(DPP0(__float_as_int(x), 0x143)));
    return x;
}
__device__ __forceinline__ unsigned wave_max_u(unsigned x) {
    x = max(x, (unsigned)DPP0((int)x, 0x111));
    x = max(x, (unsigned)DPP0((int)x, 0x112));
    x = max(x, (unsigned)DPP0((int)x, 0x114));
    x = max(x, (unsigned)DPP0((int)x, 0x118));
    x = max(x, (unsigned)DPP0((int)x, 0x142));
    x = max(x, (unsigned)DPP0((int)x, 0x143));
    return x;
}

__global__ void k_init(unsigned long long* __restrict__ keys, int BN) {
    int i = blockIdx.x * blockDim.x + threadIdx.x;
    if (i < BN) keys[i] = 0ull;
}

// grid = (ceil(A/1024), B), block 256 = 4 waves; each wave owns 256 anchors.
// launch_bounds(256,4): min 4 waves/EU -> VGPR cap 128 -> anchor state stays
// in registers (r11's VGPR=28 < live state => forced remat, 3.3x instr bloat).
__global__ __launch_bounds__(256, 4) void k_iou(
    const float4* __restrict__ gt_boxes,      // [B,N] corner boxes
    const float4* __restrict__ center_anchor, // [A] cx,cy,w,h
    unsigned long long* __restrict__ keys,    // [B,N] col-argmax keys (iou<<32|~aidx)
    unsigned long long* __restrict__ pbest,   // [B,A] row best (iou<<32|n)
    int A, int N)
{
#pragma clang fp contract(off)
    const int b     = blockIdx.y;
    const int wv    = threadIdx.x >> 6;
    const int lane  = threadIdx.x & 63;
    const int wbase = (blockIdx.x * 4 + wv) * (64 * VEC);
    const int bN    = b * N;

    // preload VEC anchors/lane; tail lanes clamp to A-1 (duplicate work is
    // value-identical -> benign for both argmaxes and the pbest store).
    float ax0[VEC], ay0[VEC], ax1[VEC], ay1[VEC], aar[VEC];
    int   aidx[VEC];
#pragma unroll
    for (int v = 0; v < VEC; ++v) {
        int a = wbase + v * 64 + lane;
        if (a >= A) a = A - 1;
        aidx[v] = a;
        float4 ca = center_anchor[a];
        float hw = ca.z * 0.5f, hh = ca.w * 0.5f;
        ax0[v] = ca.x - hw; ay0[v] = ca.y - hh;
        ax1[v] = ca.x + hw; ay1[v] = ca.y + hh;
        aar[v] = (ax1[v] - ax0[v]) * (ay1[v] - ay0[v]);   // ref: area from corners
    }
    float bv[VEC]; int bn[VEC];
#pragma unroll
    for (int v = 0; v < VEC; ++v) { bv[v] = -1.0f; bn[v] = 0; }

    for (int n = 0; n < NOBJ; ++n) {
        const float4 bx  = gt_boxes[bN + n];                 // wave-uniform -> s_load
        const float  bar = (bx.z - bx.x) * (bx.w - bx.y);    // ref op-order
        float mv = -1.0f; int ma = 0;
#pragma unroll
        for (int v = 0; v < VEC; ++v) {
            float ltx = fmaxf(ax0[v], bx.x), lty = fmaxf(ay0[v], bx.y);
            float rbx = fminf(ax1[v], bx.z), rby = fminf(ay1[v], bx.w);
            float wx = fmaxf(rbx - ltx, 0.0f), wy = fmaxf(rby - lty, 0.0f);
            float inter = wx * wy;
            float iou = inter / ((aar[v] + bar) - inter);    // IEEE div, un-fused
            if (iou > bv[v]) { bv[v] = iou; bn[v] = n; }     // row first-max over n
            if (iou > mv)    { mv = iou;    ma = aidx[v]; }  // col first-max (asc v)
        }
        // column reduce across the wave: max value, then min anchor idx among ties
        float r = wave_max_f(mv);                            // iou >= 0 -> DPP-0 safe
        unsigned wmb = (unsigned)__builtin_amdgcn_readlane(__float_as_int(r), 63);
        float wmax = __uint_as_float(wmb);
        unsigned c = (mv == wmax) ? ~(unsigned)ma : 0u;      // ~idx: max == smallest idx
        c = wave_max_u(c);
        unsigned wc = (unsigned)__builtin_amdgcn_readlane((int)c, 63);
        if (lane == 0)
            atomicMax(&keys[bN + n], ((unsigned long long)wmb << 32) | wc);
    }
    const size_t base = (size_t)b * A;
#pragma unroll
    for (int v = 0; v < VEC; ++v) {
        pbest[base + aidx[v]] =
            ((unsigned long long)__float_as_uint(bv[v]) << 32) |
            (unsigned long long)(unsigned)bn[v];
    }
}

// grid = (ceil(A/256), B), block 256. No IoU divisions here.
__global__ __launch_bounds__(256) void k_final(
    const float4* __restrict__ gt_boxes,      // [B,N]
    const int*    __restrict__ gt_labels,     // [B,N]
    const float4* __restrict__ center_anchor, // [A]
    const unsigned long long* __restrict__ keys,  // [B,N]
    const unsigned long long* __restrict__ pbest, // [B,A]
    float* __restrict__ out, int A, int N, int BA)
{
#pragma clang fp contract(off)
    __shared__ float4 sbox[NOBJ];
    __shared__ int    slab[NOBJ];
    __shared__ int    sfo[NOBJ];   // forced anchor idx per object
    const int b = blockIdx.y, tid = threadIdx.x, bN = b * N;
    if (tid < NOBJ) {
        sbox[tid] = gt_boxes[bN + tid];
        slab[tid] = gt_labels[bN + tid];
        sfo[tid]  = (int)(~(unsigned)(keys[bN + tid] & 0xffffffffull));
    }
    __syncthreads();

    const int a = blockIdx.x * 256 + tid;
    if (a >= A) return;
    const size_t ia = (size_t)b * A + a;

    const unsigned long long pb = pbest[ia];
    const float bvv = __uint_as_float((unsigned)(pb >> 32));
    const int   bnn = (int)(pb & 0xffffffffull);

    // fid = smallest object index force-matched to this anchor (or FSENT)
    int fid = FSENT;
#pragma unroll
    for (int n = 0; n < NOBJ; ++n) {
        int cn = (sfo[n] == a) ? n : FSENT;
        fid = min(fid, cn);
    }

    bool pos; int best;
    if (fid != FSENT) {
        pos  = true;   // forced 1.0 in row
        best = (bvv == 1.0f && bnn < fid) ? bnn : fid;   // numpy first-max on modified row
    } else {
        pos  = (bvv >= 0.5f);
        best = bnn;
    }
    const int cls = pos ? (slab[best] + 1) : 0;

    const float4 ca = center_anchor[a];
    const float4 gb = sbox[best];
    const float gcx = (gb.x + gb.z) * 0.5f;
    const float gcy = (gb.y + gb.w) * 0.5f;
    const float gw  = gb.z - gb.x;
    const float gh  = gb.w - gb.y;
    const float l0 = (gcx - ca.x) / (ca.z / 10.0f);
    const float l1 = (gcy - ca.y) / (ca.w / 10.0f);
    const float l2 = __logf(gw / ca.z) * 5.0f;
    const float l3 = __logf(gh / ca.w) * 5.0f;

    const int idx = b * A + a;
    out[idx] = (float)cls;                                   // classes
    reinterpret_cast<float4*>(out + (size_t)BA)[idx] =
        make_float4(l0, l1, l2, l3);                         // locations
    out[(size_t)5 * BA + idx] = pos ? 1.0f : 0.0f;           // masks
}

extern "C" void kernel_launch(void* const* d_in, const int* in_sizes, int n_in,
                              void* d_out, int out_size, void* d_ws, size_t ws_size,
                              hipStream_t stream) {
    const float4* gt_boxes      = (const float4*)d_in[0];
    const int*    gt_labels     = (const int*)d_in[1];
    const float4* center_anchor = (const float4*)d_in[2];

    const int N  = NOBJ;
    const int BN = in_sizes[1];       // B*N
    const int B  = BN / N;
    const int A  = in_sizes[2] / 4;
    const int BA = B * A;
    float* out = (float*)d_out;

    char* w = (char*)d_ws;
    unsigned long long* keys  = (unsigned long long*)w;                 // 32 KB
    unsigned long long* pbest = (unsigned long long*)(w + (size_t)BN * 8);

    k_init<<<(BN + 255) / 256, 256, 0, stream>>>(keys, BN);

    const int APB = 4 * 64 * VEC;                 // 1024 anchors per block
    dim3 g1((A + APB - 1) / APB, B);              // (24, 64)
    k_iou<<<g1, 256, 0, stream>>>(gt_boxes, center_anchor, keys, pbest, A, N);

    dim3 g2((A + 255) / 256, B);                  // (96, 64)
    k_final<<<g2, 256, 0, stream>>>(gt_boxes, gt_labels, center_anchor,
                                    keys, pbest, out, A, N, BA);
}